// Round 1
// baseline (514.162 us; speedup 1.0000x reference)
//
#include <hip/hip_runtime.h>

#define NPTS 8192
#define NROWS 4096   // 64 batch * 64 ch

// ws layout (floats):
//   tc : [0,      131072)   cos table  tc[k*8192+n] = cos(2*pi*k*n/8192)
//   ts : [131072, 262144)   sin table
//   X  : [262144, 393216)   X[row*32 + 2k] = re, +1 = im   (row = b*64 + in_ch)
//   yc : [393216, 524288)   yc[row*32 + k] = cos-coef, [row*32+16+k] = sin-coef

__global__ __launch_bounds__(256) void basis_kernel(float* __restrict__ tc,
                                                    float* __restrict__ ts) {
    int idx = blockIdx.x * 256 + threadIdx.x;   // [0, 131072)
    int k = idx >> 13;
    int n = idx & 8191;
    int phase = (k * n) & 8191;                 // exact integer arg reduction
    float a = (float)phase * (1.0f / 4096.0f);  // angle in units of pi (exact dyadic)
    tc[idx] = cospif(a);
    ts[idx] = sinpif(a);
}

// Stage 1: X[row][k] = sum_n x[row][n] * exp(-2*pi*i*k*n/N), k = 0..15
// 512 blocks x 256 thr; block handles 8 rows. LDS chunks of 128 samples.
// Thread group (32 lanes) owns 4 rows x 4 modes register tile.
__global__ __launch_bounds__(256) void dft_kernel(const float* __restrict__ x,
                                                  const float* __restrict__ tc,
                                                  const float* __restrict__ ts,
                                                  float* __restrict__ X) {
    __shared__ float xs[8 * 128];
    __shared__ float bc[16 * 128];
    __shared__ float bs[16 * 128];
    const int t = threadIdx.x;
    const int rowbase = blockIdx.x * 8;
    const int n_off = t & 31;
    const int grp = t >> 5;            // 8 groups of 32 lanes
    const int r0 = (grp & 1) * 4;      // rows r0..r0+3
    const int k0 = (grp >> 1) * 4;     // modes k0..k0+3

    float ar[4][4] = {{0.f}};
    float ai[4][4] = {{0.f}};

    for (int ch = 0; ch < 64; ++ch) {
        const int base = ch * 128;
        __syncthreads();   // previous-iter readers done before overwrite
#pragma unroll
        for (int j = 0; j < 4; ++j) {   // x chunk: 8 rows x 128
            int idx = t + j * 256;
            int r = idx >> 7, n = idx & 127;
            xs[idx] = x[(rowbase + r) * NPTS + base + n];
        }
#pragma unroll
        for (int j = 0; j < 8; ++j) {   // basis chunk: 16 modes x 128
            int idx = t + j * 256;
            int k = idx >> 7, n = idx & 127;
            bc[idx] = tc[k * NPTS + base + n];
            bs[idx] = ts[k * NPTS + base + n];
        }
        __syncthreads();
#pragma unroll
        for (int i = 0; i < 4; ++i) {
            int n = i * 32 + n_off;
            float xv[4], cv[4], sv[4];
#pragma unroll
            for (int r = 0; r < 4; ++r) xv[r] = xs[(r0 + r) * 128 + n];
#pragma unroll
            for (int j = 0; j < 4; ++j) {
                cv[j] = bc[(k0 + j) * 128 + n];
                sv[j] = bs[(k0 + j) * 128 + n];
            }
#pragma unroll
            for (int r = 0; r < 4; ++r)
#pragma unroll
                for (int j = 0; j < 4; ++j) {
                    ar[r][j] += xv[r] * cv[j];
                    ai[r][j] -= xv[r] * sv[j];
                }
        }
    }
    // reduce the 32 lanes of each group
#pragma unroll
    for (int r = 0; r < 4; ++r)
#pragma unroll
        for (int j = 0; j < 4; ++j) {
            float re = ar[r][j], im = ai[r][j];
            for (int off = 16; off > 0; off >>= 1) {
                re += __shfl_down(re, off, 32);
                im += __shfl_down(im, off, 32);
            }
            if (n_off == 0) {
                int row = rowbase + r0 + r;
                int k = k0 + j;
                X[row * 32 + k * 2]     = re;
                X[row * 32 + k * 2 + 1] = im;
            }
        }
}

// Stage 2: Y[b,o,k] = sum_i X[b,i,k] * (wr + i*wi)[i,o,k]; emit scaled
// synthesis coefs: cc[0]=ReY0/N, cc[k]=2ReYk/N, sc[k]=-2ImYk/N, sc[0]=0.
__global__ __launch_bounds__(256) void mix_kernel(const float* __restrict__ X,
                                                  const float* __restrict__ wr,
                                                  const float* __restrict__ wi,
                                                  float* __restrict__ yc) {
    __shared__ float xls[2048];   // X slice for this batch: 64 in_ch x 16 k x {re,im}
    const int t = threadIdx.x;
    const int b = blockIdx.x;
#pragma unroll
    for (int j = 0; j < 8; ++j) xls[t + j * 256] = X[b * 2048 + t + j * 256];
    __syncthreads();
    const float invn = 1.0f / 8192.0f;
#pragma unroll
    for (int i = 0; i < 4; ++i) {
        int p = t + i * 256;        // (o,k) pair
        int o = p >> 4, k = p & 15;
        float re = 0.f, im = 0.f;
        for (int ic = 0; ic < 64; ++ic) {
            float xr = xls[ic * 32 + 2 * k];
            float xi = xls[ic * 32 + 2 * k + 1];
            float wre = wr[ic * 1024 + o * 16 + k];
            float wim = wi[ic * 1024 + o * 16 + k];
            re += xr * wre - xi * wim;
            im += xr * wim + xi * wre;
        }
        int row = b * 64 + o;
        if (k == 0) {
            yc[row * 32]      = re * invn;
            yc[row * 32 + 16] = 0.f;
        } else {
            yc[row * 32 + k]      = 2.f * re * invn;
            yc[row * 32 + 16 + k] = -2.f * im * invn;
        }
    }
}

// Stage 3: out[row][n] = sum_k cc[k]*cos(2pi k n/N) + sc[k]*sin(2pi k n/N)
// 1024 blocks: (row-group of 16) x (n quarter of 2048). Basis in VGPRs,
// coefs staged in LDS, read as float4 broadcasts.
__global__ __launch_bounds__(256) void synth_kernel(const float* __restrict__ tc,
                                                    const float* __restrict__ ts,
                                                    const float* __restrict__ yc,
                                                    float* __restrict__ out) {
    __shared__ float cf[512];     // 16 rows x 32 coefs
    const int t = threadIdx.x;
    const int rg = blockIdx.x >> 2;
    const int q = blockIdx.x & 3;
    cf[t]       = yc[rg * 512 + t];
    cf[t + 256] = yc[rg * 512 + 256 + t];
    __syncthreads();
    const int rowbase = rg * 16;
#pragma unroll 1
    for (int it = 0; it < 8; ++it) {
        int n = q * 2048 + it * 256 + t;
        float cv[16], sv[16];
#pragma unroll
        for (int k = 0; k < 16; ++k) {
            cv[k] = tc[k * NPTS + n];
            sv[k] = ts[k * NPTS + n];
        }
#pragma unroll
        for (int r = 0; r < 16; ++r) {
            const float4* c4 = (const float4*)&cf[r * 32];
            float y = 0.f;
#pragma unroll
            for (int j = 0; j < 4; ++j) {
                float4 a = c4[j];
                y += a.x * cv[j * 4] + a.y * cv[j * 4 + 1] +
                     a.z * cv[j * 4 + 2] + a.w * cv[j * 4 + 3];
            }
#pragma unroll
            for (int j = 0; j < 4; ++j) {
                float4 a = c4[4 + j];
                y += a.x * sv[j * 4] + a.y * sv[j * 4 + 1] +
                     a.z * sv[j * 4 + 2] + a.w * sv[j * 4 + 3];
            }
            out[(rowbase + r) * NPTS + n] = y;
        }
    }
}

extern "C" void kernel_launch(void* const* d_in, const int* in_sizes, int n_in,
                              void* d_out, int out_size, void* d_ws, size_t ws_size,
                              hipStream_t stream) {
    const float* x  = (const float*)d_in[0];
    const float* wr = (const float*)d_in[1];
    const float* wi = (const float*)d_in[2];
    float* out = (float*)d_out;
    float* ws  = (float*)d_ws;
    float* tc = ws;
    float* ts = ws + 131072;
    float* X  = ws + 262144;
    float* yc = ws + 393216;

    basis_kernel<<<512, 256, 0, stream>>>(tc, ts);
    dft_kernel<<<512, 256, 0, stream>>>(x, tc, ts, X);
    mix_kernel<<<64, 256, 0, stream>>>(X, wr, wi, yc);
    synth_kernel<<<1024, 256, 0, stream>>>(tc, ts, yc, out);
}

// Round 2
// 373.599 us; speedup vs baseline: 1.3762x; 1.3762x over previous
//
#include <hip/hip_runtime.h>

#define NPTS 8192

// ws layout (floats), total 524288 = 2 MB (known-safe from round 1):
//   tc  [0, 131072)        cos table  tc[k*8192+n] = cos(2*pi*k*n/8192)
//   ts  [131072, 262144)   sin table
//   yc  [262144, 393216)   synth coefs: yc[row*32+k]=cos-coef, +16+k = sin-coef
//   wt  [393216, 524288)   wtr[k*4096 + i*64 + o], wti at +65536
// d_out doubles as scratch for Xp: Xp[((seg*16+k)*2+c)*4096 + row],
//   seg<4, c=0 re / 1 im, row = b*64 + in_ch.  524288 floats, overwritten by synth.

__global__ __launch_bounds__(256) void prep_kernel(const float* __restrict__ wr,
                                                   const float* __restrict__ wi,
                                                   float* __restrict__ tc,
                                                   float* __restrict__ ts,
                                                   float* __restrict__ wtr,
                                                   float* __restrict__ wti) {
    int idx = blockIdx.x * 256 + threadIdx.x;       // [0, 131072)
    int k = idx >> 13;
    int n = idx & 8191;
    int ph = (k * n) & 8191;                        // exact integer arg reduction
    float a = (float)ph * (1.0f / 4096.0f);         // angle in units of pi
    tc[idx] = cospif(a);
    ts[idx] = sinpif(a);
    if (idx < 65536) {                              // transpose weights
        int i = idx >> 10, o = (idx >> 4) & 63, kk = idx & 15;
        int dst = kk * 4096 + i * 64 + o;
        wtr[dst] = wr[idx];
        wti[dst] = wi[idx];
    }
}

// Stage 1: Xp[seg][k][c][row] = sum over seg's 2048 n of x[row][n]*e^{-i 2pi k n/N}
// grid 1024: (256 row-blocks of 16 rows) x (4 n-segments).
// 8 groups of 32 lanes: group owns 8 rows x 4 modes (64 accum VGPRs).
__global__ __launch_bounds__(256, 4) void dft_kernel(const float* __restrict__ x,
                                                     const float* __restrict__ tc,
                                                     const float* __restrict__ ts,
                                                     float* __restrict__ Xp) {
    __shared__ float4 xs4[512];    // 16 rows x 128 n
    __shared__ float4 bc4[512];    // 16 k x 128 n
    __shared__ float4 bs4[512];
    const float2* xs2 = (const float2*)xs4;
    const float2* bc2 = (const float2*)bc4;
    const float2* bs2 = (const float2*)bs4;
    const int t = threadIdx.x;
    const int rb = blockIdx.x >> 2;
    const int seg = blockIdx.x & 3;
    const int rowbase = rb * 16;
    const int segbase = seg * 2048;
    const int lane = t & 31;
    const int grp = t >> 5;
    const int r0 = (grp & 1) * 8;
    const int k0 = (grp >> 1) * 4;

    float ar[8][4] = {{0.f}};
    float ai[8][4] = {{0.f}};

    for (int ch = 0; ch < 16; ++ch) {
        const int base = segbase + ch * 128;
        __syncthreads();                 // previous-iter readers done
#pragma unroll
        for (int j = 0; j < 2; ++j) {    // stage x: 512 float4, 2/thread
            int p = t + j * 256;
            int r = p >> 5, n4 = p & 31;
            xs4[p] = *(const float4*)&x[(rowbase + r) * NPTS + base + n4 * 4];
            bc4[p] = *(const float4*)&tc[r * NPTS + base + n4 * 4];   // r == k here
            bs4[p] = *(const float4*)&ts[r * NPTS + base + n4 * 4];
        }
        __syncthreads();
#pragma unroll
        for (int i = 0; i < 2; ++i) {
            int n2 = i * 32 + lane;      // pair index in [0,64)
            float2 xv[8], cv[4], sv[4];
#pragma unroll
            for (int r = 0; r < 8; ++r) xv[r] = xs2[(r0 + r) * 64 + n2];
#pragma unroll
            for (int j = 0; j < 4; ++j) {
                cv[j] = bc2[(k0 + j) * 64 + n2];
                sv[j] = bs2[(k0 + j) * 64 + n2];
            }
#pragma unroll
            for (int r = 0; r < 8; ++r)
#pragma unroll
                for (int j = 0; j < 4; ++j) {
                    ar[r][j] += xv[r].x * cv[j].x + xv[r].y * cv[j].y;
                    ai[r][j] -= xv[r].x * sv[j].x + xv[r].y * sv[j].y;
                }
        }
    }
#pragma unroll
    for (int r = 0; r < 8; ++r)
#pragma unroll
        for (int j = 0; j < 4; ++j) {
            float re = ar[r][j], im = ai[r][j];
            for (int m = 16; m > 0; m >>= 1) {
                re += __shfl_xor(re, m, 32);
                im += __shfl_xor(im, m, 32);
            }
            if (lane == 0) {
                int row = rowbase + r0 + r;
                int k = k0 + j;
                Xp[((seg * 16 + k) * 2 + 0) * 4096 + row] = re;
                Xp[((seg * 16 + k) * 2 + 1) * 4096 + row] = im;
            }
        }
}

// Stage 2: one block per mode k. Sums 4 seg-partials, mixes channels,
// emits scaled synthesis coefs. Register tile 4 batches x 4 out_ch.
__global__ __launch_bounds__(256) void mix_kernel(const float* __restrict__ Xp,
                                                  const float* __restrict__ wtr,
                                                  const float* __restrict__ wti,
                                                  float* __restrict__ yc) {
    __shared__ float xre[64 * 65];   // [b*65 + i], padded
    __shared__ float xim[64 * 65];
    __shared__ float wlr[4096];      // [i*64 + o]
    __shared__ float wli[4096];
    const int t = threadIdx.x;
    const int k = blockIdx.x;
#pragma unroll
    for (int j = 0; j < 16; ++j) {
        int row = t + j * 256;                 // row = b*64 + i
        float re = 0.f, im = 0.f;
#pragma unroll
        for (int s = 0; s < 4; ++s) {
            re += Xp[((s * 16 + k) * 2 + 0) * 4096 + row];
            im += Xp[((s * 16 + k) * 2 + 1) * 4096 + row];
        }
        int b = row >> 6, i = row & 63;
        xre[b * 65 + i] = re;
        xim[b * 65 + i] = im;
        wlr[row] = wtr[k * 4096 + row];        // coalesced
        wli[row] = wti[k * 4096 + row];
    }
    __syncthreads();
    const int bq = t >> 4;       // batch tile: b = bq*4 .. +3
    const int oq = t & 15;       // out_ch tile: o = oq*4 .. +3
    float accr[4][4] = {{0.f}}, acci[4][4] = {{0.f}};
    for (int i = 0; i < 64; ++i) {
        float xr_[4], xi_[4];
#pragma unroll
        for (int bb = 0; bb < 4; ++bb) {
            xr_[bb] = xre[(bq * 4 + bb) * 65 + i];
            xi_[bb] = xim[(bq * 4 + bb) * 65 + i];
        }
        float4 w4r = *(const float4*)&wlr[i * 64 + oq * 4];
        float4 w4i = *(const float4*)&wli[i * 64 + oq * 4];
        float wr_[4] = {w4r.x, w4r.y, w4r.z, w4r.w};
        float wi_[4] = {w4i.x, w4i.y, w4i.z, w4i.w};
#pragma unroll
        for (int bb = 0; bb < 4; ++bb)
#pragma unroll
            for (int oo = 0; oo < 4; ++oo) {
                accr[bb][oo] += xr_[bb] * wr_[oo] - xi_[bb] * wi_[oo];
                acci[bb][oo] += xr_[bb] * wi_[oo] + xi_[bb] * wr_[oo];
            }
    }
    const float invn = 1.0f / 8192.0f;
#pragma unroll
    for (int bb = 0; bb < 4; ++bb)
#pragma unroll
        for (int oo = 0; oo < 4; ++oo) {
            int row = (bq * 4 + bb) * 64 + oq * 4 + oo;
            if (k == 0) {
                yc[row * 32]      = accr[bb][oo] * invn;
                yc[row * 32 + 16] = 0.f;
            } else {
                yc[row * 32 + k]      = 2.f * accr[bb][oo] * invn;
                yc[row * 32 + 16 + k] = -2.f * acci[bb][oo] * invn;
            }
        }
}

// Stage 3: out[row][n] = sum_k cc[k]*cos + sc[k]*sin.
// grid 4096: (512 row-groups of 8) x (8 n-ranges of 1024). Thread owns 4 n.
// Basis hoisted to VGPRs in two k-halves; coefs via b128 LDS broadcasts.
__global__ __launch_bounds__(256) void synth_kernel(const float* __restrict__ tc,
                                                    const float* __restrict__ ts,
                                                    const float* __restrict__ yc,
                                                    float* __restrict__ out) {
    __shared__ float cf[256];        // 8 rows x 32 coefs
    const int t = threadIdx.x;
    const int rg = blockIdx.x >> 3;
    const int q = blockIdx.x & 7;
    cf[t] = yc[rg * 256 + t];
    __syncthreads();
    const int n = q * 1024 + t * 4;
    float4 acc[8];
#pragma unroll
    for (int r = 0; r < 8; ++r) acc[r] = make_float4(0.f, 0.f, 0.f, 0.f);
#pragma unroll
    for (int kc = 0; kc < 2; ++kc) {           // k-halves of 8
        float4 cb[8], sb[8];
#pragma unroll
        for (int j = 0; j < 8; ++j) {
            int k = kc * 8 + j;
            cb[j] = *(const float4*)&tc[k * NPTS + n];
            sb[j] = *(const float4*)&ts[k * NPTS + n];
        }
#pragma unroll
        for (int r = 0; r < 8; ++r) {
            const float4* c4 = (const float4*)&cf[r * 32];
#pragma unroll
            for (int j2 = 0; j2 < 2; ++j2) {
                float4 a = c4[kc * 2 + j2];        // cos coefs
                float4 s = c4[4 + kc * 2 + j2];    // sin coefs
                int j0 = j2 * 4;
                acc[r].x += a.x * cb[j0].x + a.y * cb[j0 + 1].x + a.z * cb[j0 + 2].x + a.w * cb[j0 + 3].x
                          + s.x * sb[j0].x + s.y * sb[j0 + 1].x + s.z * sb[j0 + 2].x + s.w * sb[j0 + 3].x;
                acc[r].y += a.x * cb[j0].y + a.y * cb[j0 + 1].y + a.z * cb[j0 + 2].y + a.w * cb[j0 + 3].y
                          + s.x * sb[j0].y + s.y * sb[j0 + 1].y + s.z * sb[j0 + 2].y + s.w * sb[j0 + 3].y;
                acc[r].z += a.x * cb[j0].z + a.y * cb[j0 + 1].z + a.z * cb[j0 + 2].z + a.w * cb[j0 + 3].z
                          + s.x * sb[j0].z + s.y * sb[j0 + 1].z + s.z * sb[j0 + 2].z + s.w * sb[j0 + 3].z;
                acc[r].w += a.x * cb[j0].w + a.y * cb[j0 + 1].w + a.z * cb[j0 + 2].w + a.w * cb[j0 + 3].w
                          + s.x * sb[j0].w + s.y * sb[j0 + 1].w + s.z * sb[j0 + 2].w + s.w * sb[j0 + 3].w;
            }
        }
    }
#pragma unroll
    for (int r = 0; r < 8; ++r)
        *(float4*)&out[(rg * 8 + r) * NPTS + n] = acc[r];
}

extern "C" void kernel_launch(void* const* d_in, const int* in_sizes, int n_in,
                              void* d_out, int out_size, void* d_ws, size_t ws_size,
                              hipStream_t stream) {
    const float* x  = (const float*)d_in[0];
    const float* wr = (const float*)d_in[1];
    const float* wi = (const float*)d_in[2];
    float* out = (float*)d_out;
    float* ws  = (float*)d_ws;
    float* tc  = ws;
    float* ts  = ws + 131072;
    float* yc  = ws + 262144;
    float* wtr = ws + 393216;
    float* wti = ws + 458752;
    float* Xp  = out;   // scratch; overwritten by synth

    prep_kernel<<<512, 256, 0, stream>>>(wr, wi, tc, ts, wtr, wti);
    dft_kernel<<<1024, 256, 0, stream>>>(x, tc, ts, Xp);
    mix_kernel<<<16, 256, 0, stream>>>(Xp, wtr, wti, yc);
    synth_kernel<<<4096, 256, 0, stream>>>(tc, ts, yc, out);
}